// Round 9
// baseline (451.308 us; speedup 1.0000x reference)
//
#include <hip/hip_runtime.h>
#include <hip/hip_bf16.h>

#define ELL_D 64   // max in-degree slots; Poisson(16) => P(deg>=64) ~ 2e-18/node

typedef __attribute__((ext_vector_type(8))) short short8;
typedef __attribute__((ext_vector_type(4))) float f32x4;

__device__ __forceinline__ unsigned short f2bf(float f) {
    __hip_bfloat16 h = __float2bfloat16(f);  // RNE
    return *(unsigned short*)&h;
}
__device__ __forceinline__ float bf2f(unsigned short u) {
    unsigned int v = ((unsigned int)u) << 16;
    return __uint_as_float(v);
}

// ---------------- gemm1 body (f32 vector): A1(bf16 row-major, unscaled) = x @ W0 ----------------

__device__ __forceinline__ void gemm_body(int bid, const float* __restrict__ H,
                                          const float* __restrict__ W, unsigned short* __restrict__ A,
                                          int N, float4* wl4) {
    int tid = threadIdx.x;
    const float4* __restrict__ W4 = (const float4*)W;
    int tc = tid & 15;
    int tr = tid >> 4;
    int rbase = bid * 64 + tr * 4;

    const float4* __restrict__ H4 = (const float4*)H;
    float acc[4][8] = {};
    int r[4];
#pragma unroll
    for (int j = 0; j < 4; j++) {
        int rr = rbase + j;
        r[j] = (rr < N) ? rr : (N - 1);
    }

    for (int p = 0; p < 2; p++) {
        if (p) __syncthreads();
#pragma unroll
        for (int i = 0; i < 8; i++) wl4[i * 256 + tid] = W4[p * 2048 + i * 256 + tid];
        __syncthreads();
#pragma unroll 4
        for (int k4 = 0; k4 < 16; k4++) {
            union { float4 v; float f[4]; } hu[4];
#pragma unroll
            for (int j = 0; j < 4; j++) hu[j].v = H4[r[j] * 32 + p * 16 + k4];
#pragma unroll
            for (int kk = 0; kk < 4; kk++) {
                float4 w0 = wl4[(k4 * 4 + kk) * 32 + tc];
                float4 w1 = wl4[(k4 * 4 + kk) * 32 + 16 + tc];
#pragma unroll
                for (int j = 0; j < 4; j++) {
                    float h = hu[j].f[kk];
                    acc[j][0] = fmaf(h, w0.x, acc[j][0]);
                    acc[j][1] = fmaf(h, w0.y, acc[j][1]);
                    acc[j][2] = fmaf(h, w0.z, acc[j][2]);
                    acc[j][3] = fmaf(h, w0.w, acc[j][3]);
                    acc[j][4] = fmaf(h, w1.x, acc[j][4]);
                    acc[j][5] = fmaf(h, w1.y, acc[j][5]);
                    acc[j][6] = fmaf(h, w1.z, acc[j][6]);
                    acc[j][7] = fmaf(h, w1.w, acc[j][7]);
                }
            }
        }
    }

    ushort4* __restrict__ A4 = (ushort4*)A;
#pragma unroll
    for (int j = 0; j < 4; j++) {
        int rr = rbase + j;
        if (rr < N) {
            A4[rr * 32 + tc]      = make_ushort4(f2bf(acc[j][0]), f2bf(acc[j][1]), f2bf(acc[j][2]), f2bf(acc[j][3]));
            A4[rr * 32 + 16 + tc] = make_ushort4(f2bf(acc[j][4]), f2bf(acc[j][5]), f2bf(acc[j][6]), f2bf(acc[j][7]));
        }
    }
}

// ---------------- ELL fill (R6 form: 4 edges/thread, positional atomic) ----------------

__device__ __forceinline__ void fill_body(int bid, const int* __restrict__ col, const int* __restrict__ row,
                                          int* __restrict__ cnt, int* __restrict__ ell, int E) {
    int t = bid * 256 + threadIdx.x;
    int base = t * 4;
    if (base + 4 <= E) {
        int4 c4 = *(const int4*)(col + base);
        int4 r4 = *(const int4*)(row + base);
        int p0 = atomicAdd(&cnt[c4.x], 1) & 63;
        int p1 = atomicAdd(&cnt[c4.y], 1) & 63;
        int p2 = atomicAdd(&cnt[c4.z], 1) & 63;
        int p3 = atomicAdd(&cnt[c4.w], 1) & 63;
        ell[c4.x * ELL_D + p0] = r4.x;
        ell[c4.y * ELL_D + p1] = r4.y;
        ell[c4.z * ELL_D + p2] = r4.z;
        ell[c4.w * ELL_D + p3] = r4.w;
    } else {
        for (int e = base; e < E; e++) {
            int c = col[e];
            int pos = atomicAdd(&cnt[c], 1) & 63;
            ell[c * ELL_D + pos] = row[e];
        }
    }
}

__global__ __launch_bounds__(256) void k_fused(const float* __restrict__ H, const float* __restrict__ W,
                                               unsigned short* __restrict__ A,
                                               const int* __restrict__ col, const int* __restrict__ row,
                                               int* __restrict__ cnt, int* __restrict__ ell,
                                               int N, int E, int gb, int fb) {
    __shared__ float4 wl4[2048];  // 32KB (gemm blocks only)
    int half = blockIdx.x >> 1;
    if (!(blockIdx.x & 1)) {
        if (half < gb) gemm_body(half, H, W, A, N, wl4);
    } else {
        if (half < fb) fill_body(half, col, row, cnt, ell, E);
    }
}

// ---------------- W prep: WT (bf16, transposed) for layers 2,3 ----------------
__global__ __launch_bounds__(256) void k_prep_wt(const float* __restrict__ W1, const float* __restrict__ W2,
                                                 unsigned short* __restrict__ WT1, unsigned short* __restrict__ WT2) {
    const float* W = blockIdx.x ? W2 : W1;
    unsigned short* WT = blockIdx.x ? WT2 : WT1;
    for (int i = threadIdx.x; i < 16384; i += 256) {
        int c = i >> 7, k = i & 127;
        WT[i] = f2bf(W[k * 128 + c]);  // WT[c][k] = W[k][c]
    }
}

// ---------------- scaleA + dinv + ELL pad (self slot + sentinel N to multiple of 4) ----------------
// Also zeroes row N (sentinel zero row) of both A buffers.

__global__ __launch_bounds__(256) void k_scaleA_pad(const int* __restrict__ cnt, float* __restrict__ dinv,
                                                    unsigned short* __restrict__ A1, unsigned short* __restrict__ A2,
                                                    int* __restrict__ ell, int N) {
    int node = blockIdx.x * 8 + (threadIdx.x >> 5);
    int li = threadIdx.x & 31;
    if (node < N) {
        int deg = cnt[node];
        float dn = 1.0f / sqrtf((float)(deg + 1));
        if (deg > 63) deg = 63;
        if (li == 0) dinv[node] = dn;
        ushort4* Ap = (ushort4*)A1 + (size_t)node * 32 + li;
        ushort4 v = *Ap;
        v.x = f2bf(bf2f(v.x) * dn);
        v.y = f2bf(bf2f(v.y) * dn);
        v.z = f2bf(bf2f(v.z) * dn);
        v.w = f2bf(bf2f(v.w) * dn);
        *Ap = v;
        int pend = (deg + 4) & ~3;  // padded slot count (self at deg, N-sentinel to pend)
        int* er = ell + (size_t)node * ELL_D;
        if (li == 0) er[deg] = node;
        else if (li < 4 && deg + li < pend) er[deg + li] = N;
    }
    if (blockIdx.x == 0) {
        int t = threadIdx.x;
        if (t < 64) {
            ushort4 z = make_ushort4(0, 0, 0, 0);
            if (t < 32) ((ushort4*)A1)[(size_t)N * 32 + t] = z;
            else        ((ushort4*)A2)[(size_t)N * 32 + (t - 32)] = z;
        }
    }
}

// ---------------- agg quad-loop core (mask-free, pre-scaled rows => plain sum) ----------------
// Returns per-lane float4 partial for node n; caller combines halves.

__device__ __forceinline__ void agg_core(const ushort4* __restrict__ A4r, const int* __restrict__ cnt,
                                         const int* __restrict__ ell, int n, int hi, int li,
                                         float4& a0, float4& a1) {
    int deg = cnt[n];
    if (deg > 63) deg = 63;
    int nq = (deg + 4) >> 2;  // ceil((deg+1)/4), slots padded with self + N-sentinels
    const int4* __restrict__ l4 = (const int4*)(ell + (size_t)n * ELL_D);
    int q = 0;
    for (; q + 2 <= nq; q += 2) {
        int4 qa = l4[q], qb = l4[q + 1];
        int e0 = hi ? qa.y : qa.x, e1 = hi ? qa.w : qa.z;
        int e2 = hi ? qb.y : qb.x, e3 = hi ? qb.w : qb.z;
        ushort4 v0 = A4r[(size_t)e0 * 32 + li];
        ushort4 v1 = A4r[(size_t)e1 * 32 + li];
        ushort4 v2 = A4r[(size_t)e2 * 32 + li];
        ushort4 v3 = A4r[(size_t)e3 * 32 + li];
        a0.x += bf2f(v0.x) + bf2f(v1.x);
        a0.y += bf2f(v0.y) + bf2f(v1.y);
        a0.z += bf2f(v0.z) + bf2f(v1.z);
        a0.w += bf2f(v0.w) + bf2f(v1.w);
        a1.x += bf2f(v2.x) + bf2f(v3.x);
        a1.y += bf2f(v2.y) + bf2f(v3.y);
        a1.z += bf2f(v2.z) + bf2f(v3.z);
        a1.w += bf2f(v2.w) + bf2f(v3.w);
    }
    if (q < nq) {
        int4 qa = l4[q];
        int e0 = hi ? qa.y : qa.x, e1 = hi ? qa.w : qa.z;
        ushort4 v0 = A4r[(size_t)e0 * 32 + li];
        ushort4 v1 = A4r[(size_t)e1 * 32 + li];
        a0.x += bf2f(v0.x) + bf2f(v1.x);
        a0.y += bf2f(v0.y) + bf2f(v1.y);
        a0.z += bf2f(v0.z) + bf2f(v1.z);
        a0.w += bf2f(v0.w) + bf2f(v1.w);
    }
}

// ---------------- fused agg + MFMA gemm: Aout = bf16((relu(agg(Ain)+b) @ W) * dinv[row]) ----------------
// Block = 64 nodes. Phase 1: 4 waves aggregate 16 nodes each into LDS (bf16, stride 136).
// Phase 2: MFMA gemm (A-frags from LDS, B-frags = WT from global), epilogue via LDS (aliased).

__global__ __launch_bounds__(256) void k_agg_gemm(const unsigned short* __restrict__ Ain,
                                                  const int* __restrict__ cnt, const int* __restrict__ ell,
                                                  const float* __restrict__ dinv, const float* __restrict__ bias,
                                                  const unsigned short* __restrict__ WT,
                                                  unsigned short* __restrict__ Aout, int N) {
    __shared__ char lds[33792];                  // max(64*136*2, 4*16*132*4)
    unsigned short* hb = (unsigned short*)lds;   // [64][136] bf16
    float* ep = (float*)lds;                     // [4][16][132] f32 (aliased, used after barrier)
    int tid = threadIdx.x, w = tid >> 6, l = tid & 63;
    int hi = l >> 5, li = l & 31;
    int rbase = blockIdx.x * 64;
    const ushort4* __restrict__ A4r = (const ushort4*)Ain;
    float4 bb = ((const float4*)bias)[li];

    // phase 1: aggregate 16 nodes per wave
    for (int it = 0; it < 16; ++it) {
        int lrow = w * 16 + it;
        int n = rbase + lrow;
        float4 a0 = {0, 0, 0, 0}, a1 = {0, 0, 0, 0};
        if (n < N) {
            agg_core(A4r, cnt, ell, n, hi, li, a0, a1);
            a0.x += a1.x; a0.y += a1.y; a0.z += a1.z; a0.w += a1.w;
            a0.x += __shfl_xor(a0.x, 32, 64);
            a0.y += __shfl_xor(a0.y, 32, 64);
            a0.z += __shfl_xor(a0.z, 32, 64);
            a0.w += __shfl_xor(a0.w, 32, 64);
        }
        if (hi == 0) {
            float dn = (n < N) ? dinv[n] : 0.f;
            ushort4 o;
            o.x = f2bf(fmaxf(fmaf(a0.x, dn, bb.x), 0.f));
            o.y = f2bf(fmaxf(fmaf(a0.y, dn, bb.y), 0.f));
            o.z = f2bf(fmaxf(fmaf(a0.z, dn, bb.z), 0.f));
            o.w = f2bf(fmaxf(fmaf(a0.w, dn, bb.w), 0.f));
            *(ushort4*)(hb + (size_t)lrow * 136 + li * 4) = o;
        }
    }
    __syncthreads();

    // phase 2: MFMA gemm on the 64 aggregated rows
    int lrow16 = l & 15, lk = l >> 4;
    const unsigned short* hrow = hb + (size_t)(w * 16 + lrow16) * 136;
    short8 af[4];
#pragma unroll
    for (int kc = 0; kc < 4; kc++) af[kc] = *(const short8*)(hrow + kc * 32 + lk * 8);
    __syncthreads();  // LDS now reusable as ep

    f32x4 acc[8];
#pragma unroll
    for (int t = 0; t < 8; t++) {
        f32x4 a = {0.f, 0.f, 0.f, 0.f};
        const short8* __restrict__ Wp = (const short8*)(WT + (size_t)(t * 16 + lrow16) * 128);
#pragma unroll
        for (int kc = 0; kc < 4; kc++) {
            short8 bf = Wp[kc * 4 + lk];
            a = __builtin_amdgcn_mfma_f32_16x16x32_bf16(af[kc], bf, a, 0, 0, 0);
        }
        acc[t] = a;
    }

    float* base = ep + w * 2112;
#pragma unroll
    for (int t = 0; t < 8; t++)
#pragma unroll
        for (int j = 0; j < 4; j++)
            base[(4 * lk + j) * 132 + t * 16 + lrow16] = acc[t][j];
    __syncthreads();

    int row16 = l >> 2, c0 = (l & 3) * 32;
    int orow = rbase + w * 16 + row16;
    if (orow < N) {
        float dn = dinv[orow];
        const float* src = base + row16 * 132 + c0;
        unsigned short* dst = Aout + (size_t)orow * 128 + c0;
#pragma unroll
        for (int q = 0; q < 4; q++) {
            union { short8 s8; unsigned short u[8]; } pk;
#pragma unroll
            for (int e = 0; e < 8; e++) pk.u[e] = f2bf(src[q * 8 + e] * dn);
            *(short8*)(dst + q * 8) = pk.s8;
        }
    }
}

// ---------------- plain agg (layer 3 -> pool): Bout = bf16(relu(dinv*sum + bias)) ----------------

__global__ __launch_bounds__(256) void k_agg(const unsigned short* __restrict__ Ain, const int* __restrict__ cnt,
                                             const int* __restrict__ ell, const float* __restrict__ dinv,
                                             const float* __restrict__ bias, unsigned short* __restrict__ Bout, int N) {
    int wid = blockIdx.x * 4 + (threadIdx.x >> 6);
    int lane = threadIdx.x & 63;
    if (wid >= N) return;
    int hi = lane >> 5, li = lane & 31;
    const ushort4* __restrict__ A4r = (const ushort4*)Ain;
    float4 a0 = {0, 0, 0, 0}, a1 = {0, 0, 0, 0};
    agg_core(A4r, cnt, ell, wid, hi, li, a0, a1);
    a0.x += a1.x; a0.y += a1.y; a0.z += a1.z; a0.w += a1.w;
    a0.x += __shfl_xor(a0.x, 32, 64);
    a0.y += __shfl_xor(a0.y, 32, 64);
    a0.z += __shfl_xor(a0.z, 32, 64);
    a0.w += __shfl_xor(a0.w, 32, 64);
    if (hi == 0) {
        float dn = dinv[wid];
        float4 bb = ((const float4*)bias)[li];
        ushort4 o;
        o.x = f2bf(fmaxf(fmaf(a0.x, dn, bb.x), 0.f));
        o.y = f2bf(fmaxf(fmaf(a0.y, dn, bb.y), 0.f));
        o.z = f2bf(fmaxf(fmaf(a0.z, dn, bb.z), 0.f));
        o.w = f2bf(fmaxf(fmaf(a0.w, dn, bb.w), 0.f));
        ((ushort4*)Bout)[wid * 32 + li] = o;
    }
}

// ---------------- Pool (mean per graph, sorted batch) + head; B is bf16 ----------------

__global__ __launch_bounds__(512) void k_pool(const unsigned short* __restrict__ B, const int* __restrict__ batch,
                                              const float* __restrict__ Wl, const float* __restrict__ bl,
                                              float* __restrict__ out, int N) {
    int g = blockIdx.x;
    int tid = threadIdx.x;
    int k = tid & 127, h = tid >> 7;  // h in 0..3
    __shared__ int se[2];
    __shared__ float red[4][128];
    if (tid < 2) {
        int target = g + tid;  // lower_bound(batch, target)
        int lo = 0, hi = N;
        while (lo < hi) {
            int mid = (lo + hi) >> 1;
            if (batch[mid] < target) lo = mid + 1; else hi = mid;
        }
        se[tid] = lo;
    }
    __syncthreads();
    int start = se[0], end = se[1];
    float s = 0.f;
    for (int n = start + h; n < end; n += 4) s += bf2f(B[n * 128 + k]);
    red[h][k] = s;
    __syncthreads();
    if (h == 0) {
        float tot = red[0][k] + red[1][k] + red[2][k] + red[3][k];
        int cg = end - start;
        red[0][k] = tot / (float)(cg > 1 ? cg : 1);
    }
    __syncthreads();
    if (tid < 10) {
        float o = bl[tid];
        for (int j = 0; j < 128; j++) o = fmaf(red[0][j], Wl[j * 10 + tid], o);
        out[g * 10 + tid] = o;
    }
}

// ---------------- launch ----------------

extern "C" void kernel_launch(void* const* d_in, const int* in_sizes, int n_in,
                              void* d_out, int out_size, void* d_ws, size_t ws_size,
                              hipStream_t stream) {
    const float* x  = (const float*)d_in[0];
    const int* eidx = (const int*)d_in[1];
    const int* batch = (const int*)d_in[2];
    const float* W0 = (const float*)d_in[3];
    const float* b0 = (const float*)d_in[4];
    const float* W1 = (const float*)d_in[5];
    const float* b1 = (const float*)d_in[6];
    const float* W2 = (const float*)d_in[7];
    const float* b2 = (const float*)d_in[8];
    const float* Wl = (const float*)d_in[9];
    const float* bl = (const float*)d_in[10];

    int N = in_sizes[0] / 128;
    int E = in_sizes[1] / 2;
    int G = out_size / 10;
    const int* row = eidx;      // edge_index[0] = source
    const int* col = eidx + E;  // edge_index[1] = target

    char* w = (char*)d_ws;
    auto carve = [&](size_t bytes) -> void* {
        void* p = (void*)w;
        w += (bytes + 511) & ~(size_t)511;
        return p;
    };
    unsigned short* A1 = (unsigned short*)carve((size_t)(N + 1) * 128 * 2);  // bf16, +zero row N
    unsigned short* A2 = (unsigned short*)carve((size_t)(N + 1) * 128 * 2);  // bf16, +zero row N
    unsigned short* Bb = (unsigned short*)carve((size_t)N * 128 * 2);        // bf16 (layer-3 out)
    int*   cnt  = (int*)carve((size_t)N * 4);
    float* dinv = (float*)carve((size_t)N * 4);
    int*   ell  = (int*)carve((size_t)N * ELL_D * 4);
    unsigned short* WT1 = (unsigned short*)carve(16384 * 2);
    unsigned short* WT2 = (unsigned short*)carve(16384 * 2);

    int gb = (N + 63) / 64;
    int ft = (E + 3) / 4;
    int fb = (ft + 255) / 256;
    int M  = (gb > fb) ? gb : fb;

    hipMemsetAsync(cnt, 0, (size_t)N * 4, stream);
    k_prep_wt<<<2, 256, 0, stream>>>(W1, W2, WT1, WT2);
    // layer-1 gemm (f32 vector) overlapped with ELL fill
    k_fused<<<2 * M, 256, 0, stream>>>(x, W0, A1, col, row, cnt, ell, N, E, gb, fb);
    // dinv + scale A1 + pad ELL (self slot + N-sentinels) + zero rows N
    k_scaleA_pad<<<(N + 7) / 8, 256, 0, stream>>>(cnt, dinv, A1, A2, ell, N);

    int mb = (N + 63) / 64;
    // layer-1 agg fused with layer-2 gemm
    k_agg_gemm<<<mb, 256, 0, stream>>>(A1, cnt, ell, dinv, b0, WT1, A2, N);
    // layer-2 agg fused with layer-3 gemm
    k_agg_gemm<<<mb, 256, 0, stream>>>(A2, cnt, ell, dinv, b1, WT2, A1, N);
    // layer-3 agg
    k_agg<<<(N + 3) / 4, 256, 0, stream>>>(A1, cnt, ell, dinv, b2, Bb, N);
    // pool + head
    k_pool<<<G, 512, 0, stream>>>(Bb, batch, Wl, bl, (float*)d_out, N);
}

// Round 10
// 396.183 us; speedup vs baseline: 1.1391x; 1.1391x over previous
//
#include <hip/hip_runtime.h>
#include <hip/hip_bf16.h>

#define ELL_D 64   // max in-degree slots; Poisson(16) => P(deg>=64) ~ 2e-18/node

typedef __attribute__((ext_vector_type(8))) short short8;
typedef __attribute__((ext_vector_type(4))) float f32x4;

__device__ __forceinline__ unsigned short f2bf(float f) {
    __hip_bfloat16 h = __float2bfloat16(f);  // RNE
    return *(unsigned short*)&h;
}
__device__ __forceinline__ float bf2f(unsigned short u) {
    unsigned int v = ((unsigned int)u) << 16;
    return __uint_as_float(v);
}

// ---------------- gemm1 body (f32 vector): A(bf16 row-major, unscaled) = x @ W0 ----------------

__device__ __forceinline__ void gemm_body(int bid, const float* __restrict__ H,
                                          const float* __restrict__ W, unsigned short* __restrict__ A,
                                          int N, float4* wl4) {
    int tid = threadIdx.x;
    const float4* __restrict__ W4 = (const float4*)W;
    int tc = tid & 15;
    int tr = tid >> 4;
    int rbase = bid * 64 + tr * 4;

    const float4* __restrict__ H4 = (const float4*)H;
    float acc[4][8] = {};
    int r[4];
#pragma unroll
    for (int j = 0; j < 4; j++) {
        int rr = rbase + j;
        r[j] = (rr < N) ? rr : (N - 1);
    }

    for (int p = 0; p < 2; p++) {
        if (p) __syncthreads();
#pragma unroll
        for (int i = 0; i < 8; i++) wl4[i * 256 + tid] = W4[p * 2048 + i * 256 + tid];
        __syncthreads();
#pragma unroll 4
        for (int k4 = 0; k4 < 16; k4++) {
            union { float4 v; float f[4]; } hu[4];
#pragma unroll
            for (int j = 0; j < 4; j++) hu[j].v = H4[r[j] * 32 + p * 16 + k4];
#pragma unroll
            for (int kk = 0; kk < 4; kk++) {
                float4 w0 = wl4[(k4 * 4 + kk) * 32 + tc];
                float4 w1 = wl4[(k4 * 4 + kk) * 32 + 16 + tc];
#pragma unroll
                for (int j = 0; j < 4; j++) {
                    float h = hu[j].f[kk];
                    acc[j][0] = fmaf(h, w0.x, acc[j][0]);
                    acc[j][1] = fmaf(h, w0.y, acc[j][1]);
                    acc[j][2] = fmaf(h, w0.z, acc[j][2]);
                    acc[j][3] = fmaf(h, w0.w, acc[j][3]);
                    acc[j][4] = fmaf(h, w1.x, acc[j][4]);
                    acc[j][5] = fmaf(h, w1.y, acc[j][5]);
                    acc[j][6] = fmaf(h, w1.z, acc[j][6]);
                    acc[j][7] = fmaf(h, w1.w, acc[j][7]);
                }
            }
        }
    }

    ushort4* __restrict__ A4 = (ushort4*)A;
#pragma unroll
    for (int j = 0; j < 4; j++) {
        int rr = rbase + j;
        if (rr < N) {
            A4[rr * 32 + tc]      = make_ushort4(f2bf(acc[j][0]), f2bf(acc[j][1]), f2bf(acc[j][2]), f2bf(acc[j][3]));
            A4[rr * 32 + 16 + tc] = make_ushort4(f2bf(acc[j][4]), f2bf(acc[j][5]), f2bf(acc[j][6]), f2bf(acc[j][7]));
        }
    }
}

// ---------------- ELL fill (4 edges/thread, positional atomic) ----------------

__device__ __forceinline__ void fill_body(int bid, const int* __restrict__ col, const int* __restrict__ row,
                                          int* __restrict__ cnt, int* __restrict__ ell, int E) {
    int t = bid * 256 + threadIdx.x;
    int base = t * 4;
    if (base + 4 <= E) {
        int4 c4 = *(const int4*)(col + base);
        int4 r4 = *(const int4*)(row + base);
        int p0 = atomicAdd(&cnt[c4.x], 1) & 63;
        int p1 = atomicAdd(&cnt[c4.y], 1) & 63;
        int p2 = atomicAdd(&cnt[c4.z], 1) & 63;
        int p3 = atomicAdd(&cnt[c4.w], 1) & 63;
        ell[c4.x * ELL_D + p0] = r4.x;
        ell[c4.y * ELL_D + p1] = r4.y;
        ell[c4.z * ELL_D + p2] = r4.z;
        ell[c4.w * ELL_D + p3] = r4.w;
    } else {
        for (int e = base; e < E; e++) {
            int c = col[e];
            int pos = atomicAdd(&cnt[c], 1) & 63;
            ell[c * ELL_D + pos] = row[e];
        }
    }
}

__global__ __launch_bounds__(256) void k_fused(const float* __restrict__ H, const float* __restrict__ W,
                                               unsigned short* __restrict__ A,
                                               const int* __restrict__ col, const int* __restrict__ row,
                                               int* __restrict__ cnt, int* __restrict__ ell,
                                               int N, int E, int gb, int fb) {
    __shared__ float4 wl4[2048];  // 32KB (gemm blocks only)
    int half = blockIdx.x >> 1;
    if (!(blockIdx.x & 1)) {
        if (half < gb) gemm_body(half, H, W, A, N, wl4);
    } else {
        if (half < fb) fill_body(half, col, row, cnt, ell, E);
    }
}

// ---------------- W prep: WT (bf16, transposed) for layers 2,3 ----------------
__global__ __launch_bounds__(256) void k_prep_wt(const float* __restrict__ W1, const float* __restrict__ W2,
                                                 unsigned short* __restrict__ WT1, unsigned short* __restrict__ WT2) {
    const float* W = blockIdx.x ? W2 : W1;
    unsigned short* WT = blockIdx.x ? WT2 : WT1;
    for (int i = threadIdx.x; i < 16384; i += 256) {
        int c = i >> 7, k = i & 127;
        WT[i] = f2bf(W[k * 128 + c]);  // WT[c][k] = W[k][c]
    }
}

// ---------------- scaleA + dinv + ELL pad (self slot + N-sentinels to multiple of 8) ----------------
// Also zeroes sentinel row N of A.

__global__ __launch_bounds__(256) void k_scaleA_pad(const int* __restrict__ cnt, float* __restrict__ dinv,
                                                    unsigned short* __restrict__ A, int* __restrict__ ell, int N) {
    int node = blockIdx.x * 8 + (threadIdx.x >> 5);
    int li = threadIdx.x & 31;
    if (node < N) {
        int deg = cnt[node];
        float dn = 1.0f / sqrtf((float)(deg + 1));
        if (deg > 63) deg = 63;
        if (li == 0) dinv[node] = dn;
        ushort4* Ap = (ushort4*)A + (size_t)node * 32 + li;
        ushort4 v = *Ap;
        v.x = f2bf(bf2f(v.x) * dn);
        v.y = f2bf(bf2f(v.y) * dn);
        v.z = f2bf(bf2f(v.z) * dn);
        v.w = f2bf(bf2f(v.w) * dn);
        *Ap = v;
        int pend = (deg + 8) & ~7;  // slots: deg edges + self + sentinels, multiple of 8
        if (pend > 64) pend = 64;
        int* er = ell + (size_t)node * ELL_D;
        if (li == 0) er[deg] = node;                               // virtual self edge
        else if (li < 8 && deg + li < pend) er[deg + li] = N;      // zero-row sentinels
    }
    if (blockIdx.x == 0 && threadIdx.x < 32) {
        ((ushort4*)A)[(size_t)N * 32 + threadIdx.x] = make_ushort4(0, 0, 0, 0);
    }
}

// ---------------- Aggregation: half-wave per node, tail-free 8-deep gather loop ----------------
// A rows pre-scaled by dinv[src]; row N = zeros. Bout[n] = bf16(relu(dinv[n]*sum + bias)).

__global__ __launch_bounds__(256) void k_agg(const unsigned short* __restrict__ Ain, const int* __restrict__ cnt,
                                             const int* __restrict__ ell, const float* __restrict__ dinv,
                                             const float* __restrict__ bias, unsigned short* __restrict__ Bout, int N) {
    int lane = threadIdx.x & 63;
    int hi = lane >> 5, li = lane & 31;
    int n = blockIdx.x * 8 + ((threadIdx.x >> 6) << 1) + hi;
    if (n >= N) return;
    const ushort4* __restrict__ A4r = (const ushort4*)Ain;
    int deg = cnt[n];
    if (deg > 63) deg = 63;
    int pend = (deg + 8) & ~7;
    if (pend > 64) pend = 64;
    int nq = pend >> 2;  // even
    const int4* __restrict__ l4 = (const int4*)(ell + (size_t)n * ELL_D);

    float4 a0 = {0, 0, 0, 0}, a1 = {0, 0, 0, 0};
    for (int q = 0; q < nq; q += 2) {
        int4 qa = l4[q], qb = l4[q + 1];
        ushort4 v0 = A4r[(size_t)qa.x * 32 + li];
        ushort4 v1 = A4r[(size_t)qa.y * 32 + li];
        ushort4 v2 = A4r[(size_t)qa.z * 32 + li];
        ushort4 v3 = A4r[(size_t)qa.w * 32 + li];
        ushort4 v4 = A4r[(size_t)qb.x * 32 + li];
        ushort4 v5 = A4r[(size_t)qb.y * 32 + li];
        ushort4 v6 = A4r[(size_t)qb.z * 32 + li];
        ushort4 v7 = A4r[(size_t)qb.w * 32 + li];
        a0.x += (bf2f(v0.x) + bf2f(v1.x)) + (bf2f(v2.x) + bf2f(v3.x));
        a0.y += (bf2f(v0.y) + bf2f(v1.y)) + (bf2f(v2.y) + bf2f(v3.y));
        a0.z += (bf2f(v0.z) + bf2f(v1.z)) + (bf2f(v2.z) + bf2f(v3.z));
        a0.w += (bf2f(v0.w) + bf2f(v1.w)) + (bf2f(v2.w) + bf2f(v3.w));
        a1.x += (bf2f(v4.x) + bf2f(v5.x)) + (bf2f(v6.x) + bf2f(v7.x));
        a1.y += (bf2f(v4.y) + bf2f(v5.y)) + (bf2f(v6.y) + bf2f(v7.y));
        a1.z += (bf2f(v4.z) + bf2f(v5.z)) + (bf2f(v6.z) + bf2f(v7.z));
        a1.w += (bf2f(v4.w) + bf2f(v5.w)) + (bf2f(v6.w) + bf2f(v7.w));
    }
    float dn = dinv[n];
    float4 bb = ((const float4*)bias)[li];
    ushort4 o;
    o.x = f2bf(fmaxf(fmaf(a0.x + a1.x, dn, bb.x), 0.f));
    o.y = f2bf(fmaxf(fmaf(a0.y + a1.y, dn, bb.y), 0.f));
    o.z = f2bf(fmaxf(fmaf(a0.z + a1.z, dn, bb.z), 0.f));
    o.w = f2bf(fmaxf(fmaf(a0.w + a1.w, dn, bb.w), 0.f));
    ((ushort4*)Bout)[(size_t)n * 32 + li] = o;
}

// ---------------- MFMA GEMM (layers 2,3): A' = bf16((Bb @ W) * dinv[row]) ----------------

__global__ __launch_bounds__(256) void k_gemm_mfma(const unsigned short* __restrict__ H,
                                                   const unsigned short* __restrict__ WT,
                                                   const float* __restrict__ dinv,
                                                   unsigned short* __restrict__ A, int N) {
    __shared__ float ep[4 * 16 * 132];  // per-wave 16x128 f32, row stride 132
    int tid = threadIdx.x, w = tid >> 6, l = tid & 63;
    int rbase = blockIdx.x * 64 + w * 16;
    int lrow = l & 15, lk = l >> 4;

    int r = rbase + lrow;
    if (r >= N) r = N - 1;
    const short8* __restrict__ Hp = (const short8*)(H + (size_t)r * 128);
    short8 af[4];
#pragma unroll
    for (int kc = 0; kc < 4; kc++) af[kc] = Hp[kc * 4 + lk];

    f32x4 acc[8];
#pragma unroll
    for (int t = 0; t < 8; t++) {
        f32x4 a = {0.f, 0.f, 0.f, 0.f};
        const short8* __restrict__ Wp = (const short8*)(WT + (size_t)(t * 16 + lrow) * 128);
#pragma unroll
        for (int kc = 0; kc < 4; kc++) {
            short8 bf = Wp[kc * 4 + lk];
            a = __builtin_amdgcn_mfma_f32_16x16x32_bf16(af[kc], bf, a, 0, 0, 0);
        }
        acc[t] = a;
    }

    float* base = ep + w * 2112;
#pragma unroll
    for (int t = 0; t < 8; t++)
#pragma unroll
        for (int j = 0; j < 4; j++)
            base[(4 * lk + j) * 132 + t * 16 + lrow] = acc[t][j];
    __syncthreads();

    int row16 = l >> 2, c0 = (l & 3) * 32;
    int orow = rbase + row16;
    if (orow < N) {
        float dn = dinv[orow];
        const float* src = base + row16 * 132 + c0;
        unsigned short* dst = A + (size_t)orow * 128 + c0;
#pragma unroll
        for (int q = 0; q < 4; q++) {
            union { short8 s8; unsigned short u[8]; } pk;
#pragma unroll
            for (int e = 0; e < 8; e++) pk.u[e] = f2bf(src[q * 8 + e] * dn);
            *(short8*)(dst + q * 8) = pk.s8;
        }
    }
}

// ---------------- Pool (mean per graph, sorted batch) + head; B is bf16 ----------------

__global__ __launch_bounds__(512) void k_pool(const unsigned short* __restrict__ B, const int* __restrict__ batch,
                                              const float* __restrict__ Wl, const float* __restrict__ bl,
                                              float* __restrict__ out, int N) {
    int g = blockIdx.x;
    int tid = threadIdx.x;
    int k = tid & 127, h = tid >> 7;  // h in 0..3
    __shared__ int se[2];
    __shared__ float red[4][128];
    if (tid < 2) {
        int target = g + tid;  // lower_bound(batch, target)
        int lo = 0, hi = N;
        while (lo < hi) {
            int mid = (lo + hi) >> 1;
            if (batch[mid] < target) lo = mid + 1; else hi = mid;
        }
        se[tid] = lo;
    }
    __syncthreads();
    int start = se[0], end = se[1];
    float s = 0.f;
    for (int n = start + h; n < end; n += 4) s += bf2f(B[n * 128 + k]);
    red[h][k] = s;
    __syncthreads();
    if (h == 0) {
        float tot = red[0][k] + red[1][k] + red[2][k] + red[3][k];
        int cg = end - start;
        red[0][k] = tot / (float)(cg > 1 ? cg : 1);
    }
    __syncthreads();
    if (tid < 10) {
        float o = bl[tid];
        for (int j = 0; j < 128; j++) o = fmaf(red[0][j], Wl[j * 10 + tid], o);
        out[g * 10 + tid] = o;
    }
}

// ---------------- launch ----------------

extern "C" void kernel_launch(void* const* d_in, const int* in_sizes, int n_in,
                              void* d_out, int out_size, void* d_ws, size_t ws_size,
                              hipStream_t stream) {
    const float* x  = (const float*)d_in[0];
    const int* eidx = (const int*)d_in[1];
    const int* batch = (const int*)d_in[2];
    const float* W0 = (const float*)d_in[3];
    const float* b0 = (const float*)d_in[4];
    const float* W1 = (const float*)d_in[5];
    const float* b1 = (const float*)d_in[6];
    const float* W2 = (const float*)d_in[7];
    const float* b2 = (const float*)d_in[8];
    const float* Wl = (const float*)d_in[9];
    const float* bl = (const float*)d_in[10];

    int N = in_sizes[0] / 128;
    int E = in_sizes[1] / 2;
    int G = out_size / 10;
    const int* row = eidx;      // edge_index[0] = source
    const int* col = eidx + E;  // edge_index[1] = target

    char* w = (char*)d_ws;
    auto carve = [&](size_t bytes) -> void* {
        void* p = (void*)w;
        w += (bytes + 511) & ~(size_t)511;
        return p;
    };
    unsigned short* A  = (unsigned short*)carve((size_t)(N + 1) * 128 * 2);  // bf16, +zero row N
    unsigned short* Bb = (unsigned short*)carve((size_t)N * 128 * 2);        // bf16
    int*   cnt  = (int*)carve((size_t)N * 4);
    float* dinv = (float*)carve((size_t)N * 4);
    int*   ell  = (int*)carve((size_t)N * ELL_D * 4);
    unsigned short* WT1 = (unsigned short*)carve(16384 * 2);
    unsigned short* WT2 = (unsigned short*)carve(16384 * 2);

    int gb = (N + 63) / 64;
    int ft = (E + 3) / 4;
    int fb = (ft + 255) / 256;
    int M  = (gb > fb) ? gb : fb;

    hipMemsetAsync(cnt, 0, (size_t)N * 4, stream);
    k_prep_wt<<<2, 256, 0, stream>>>(W1, W2, WT1, WT2);
    // layer-1 gemm (f32 vector) overlapped with ELL fill
    k_fused<<<2 * M, 256, 0, stream>>>(x, W0, A, col, row, cnt, ell, N, E, gb, fb);
    // dinv + scale A + pad ELL (self + N-sentinels to x8) + zero row N
    k_scaleA_pad<<<(N + 7) / 8, 256, 0, stream>>>(cnt, dinv, A, ell, N);

    int ab = (N + 7) / 8;
    int mb = (N + 63) / 64;
    k_agg<<<ab, 256, 0, stream>>>(A, cnt, ell, dinv, b0, Bb, N);
    // layer 2
    k_gemm_mfma<<<mb, 256, 0, stream>>>(Bb, WT1, dinv, A, N);
    k_agg<<<ab, 256, 0, stream>>>(A, cnt, ell, dinv, b1, Bb, N);
    // layer 3
    k_gemm_mfma<<<mb, 256, 0, stream>>>(Bb, WT2, dinv, A, N);
    k_agg<<<ab, 256, 0, stream>>>(A, cnt, ell, dinv, b2, Bb, N);
    // pool + head
    k_pool<<<G, 512, 0, stream>>>(Bb, batch, Wl, bl, (float*)d_out, N);
}